// Round 1
// baseline (15389.371 us; speedup 1.0000x reference)
//
#include <hip/hip_runtime.h>
#include <cmath>

#define T_STEPS 16384
#define NH 361
#define NIN 489
#define NRULE 128

typedef _Float16 half8 __attribute__((ext_vector_type(8)));
typedef float f32x4 __attribute__((ext_vector_type(4)));

static constexpr double PI_D = 3.14159265358979323846;

// ---------------------------------------------------------------------------
// k0: one-time prep: transpose W2 = w_ih[:,128:] into w2t[j][i], and fold
//     A[i] = w_ih[i,:128] @ w_rule,  C[i] = w_ih[i,:128] @ b_rule + b_ih + b_hh
// ---------------------------------------------------------------------------
__global__ void k0_prep(const float* __restrict__ w_ih, const float* __restrict__ w_rule,
                        const float* __restrict__ b_rule, const float* __restrict__ b_ih,
                        const float* __restrict__ b_hh,
                        float* __restrict__ Av, float* __restrict__ Cv,
                        float* __restrict__ w2t) {
  int idx = blockIdx.x * 256 + threadIdx.x;
  if (idx < NH * NH) {
    int i = idx % NH;       // output row of w_ih
    int j = idx / NH;       // angle-grid column
    w2t[idx] = w_ih[i * NIN + NRULE + j];   // w2t[j*NH + i]
  }
  if (idx < NH) {
    float a = 0.f, c = 0.f;
    for (int k = 0; k < NRULE; ++k) {
      float w = w_ih[idx * NIN + k];
      a += w * w_rule[k];
      c += w * b_rule[k];
    }
    Av[idx] = a;
    Cv[idx] = c + b_ih[idx] + b_hh[idx];
  }
}

// ---------------------------------------------------------------------------
// k1: xw[t][i] = sum_j w2t[j][i]*vm[t][j] + rule[t]*A[i] + C[i]
//     vm[t][j] = S * exp(kappa*(cos(j*pi/180 - mu_t) - 1)),  S = e^k/(2*pi*I0(k))
//     One block = 32 timesteps; vm staged in LDS transposed [j][tt].
// ---------------------------------------------------------------------------
__global__ void k1_xw(const float* __restrict__ angle, const float* __restrict__ rule,
                      const float* __restrict__ Av, const float* __restrict__ Cv,
                      const float* __restrict__ w2t, float* __restrict__ xw,
                      float kappa, float vmS) {
  __shared__ float vm[NH][32];
  __shared__ float srule[32];
  const int tid = threadIdx.x;
  const int t0 = blockIdx.x * 32;
  const float DEG = (float)(PI_D / 180.0);

  for (int idx = tid; idx < NH * 32; idx += 256) {
    int j = idx >> 5;
    int tt = idx & 31;
    float mu = angle[t0 + tt] * DEG;
    float c = __cosf((float)j * DEG - mu);
    vm[j][tt] = vmS * __expf(kappa * (c - 1.f));
  }
  if (tid < 32) srule[tid] = rule[t0 + tid];
  __syncthreads();

  for (int i = tid; i < NH; i += 256) {
    float acc[32];
#pragma unroll
    for (int tt = 0; tt < 32; ++tt) acc[tt] = 0.f;
    for (int j = 0; j < NH; ++j) {
      float wv = w2t[j * NH + i];          // coalesced across lanes (i contiguous)
#pragma unroll
      for (int tt = 0; tt < 32; ++tt) acc[tt] += wv * vm[j][tt];  // LDS broadcast
    }
    float Ai = Av[i], Ci = Cv[i];
#pragma unroll
    for (int tt = 0; tt < 32; ++tt)
      xw[(t0 + tt) * NH + i] = acc[tt] + srule[tt] * Ai + Ci;
  }
}

// ---------------------------------------------------------------------------
// k2: sequential RNN. One workgroup, 512 threads = 8 waves, one CU.
//   out[i] = sum_k h[k]*W_hh[i][k] computed as D = A*B with
//   A (16x32): row 0 = h k-slice (rows 1..15 zero) -- read from LDS, pre-laid
//              out in A-fragment order (lane = ((k>>3)&3)*16, elem = k&7).
//   B (32x16): B[kk][c] = W_hh[16*ct + c][32*kt + kk] -- static in VGPRs (f16).
//   D row 0 lands on lanes 0..15, reg 0 (C/D layout: col=lane&15, row=(lane>>4)*4+reg).
//   Wave w owns coltiles 3w..3w+2 (48 outputs). 12 ktiles cover K=384 (padded).
// ---------------------------------------------------------------------------
__global__ __launch_bounds__(512, 2) void k2_rnn(const float* __restrict__ w_hh,
                                                 const float* __restrict__ xw,
                                                 float* __restrict__ hs) {
  __shared__ _Float16 afrag[2][12][64][8];   // 24576 B, double-buffered h in A-frag layout
  const int tid = threadIdx.x;
  const int wv = tid >> 6;
  const int lane = tid & 63;
  const int l15 = lane & 15;
  const int lhi = lane >> 4;

  // zero both buffers once (pad rows/cols stay zero forever)
  int* lp = (int*)&afrag[0][0][0][0];
  for (int idx = tid; idx < 6144; idx += 512) lp[idx] = 0;

  // Load W_hh as B fragments (f16), static for the whole loop: 144 VGPRs.
  half8 bw[3][12];
#pragma unroll
  for (int ct = 0; ct < 3; ++ct) {
    const int i = (wv * 3 + ct) * 16 + l15;
#pragma unroll
    for (int kt = 0; kt < 12; ++kt) {
      half8 v;
#pragma unroll
      for (int e = 0; e < 8; ++e) {
        const int k = kt * 32 + lhi * 8 + e;
        float x = (i < NH && k < NH) ? w_hh[i * NH + k] : 0.f;
        v[e] = (_Float16)x;
      }
      bw[ct][kt] = v;
    }
  }

  const int ib = (wv * 3) * 16 + l15;   // first owned output index (lanes>=16 mirror 0..15)
  float xwv0 = (ib < NH) ? xw[ib] : 0.f;
  float xwv1 = (ib + 16 < NH) ? xw[ib + 16] : 0.f;
  float xwv2 = (ib + 32 < NH) ? xw[ib + 32] : 0.f;
  __syncthreads();

  const f32x4 zero4 = {0.f, 0.f, 0.f, 0.f};
  for (int t = 0; t < T_STEPS; ++t) {
    // prefetch next step's xw (hidden under MFMA phase)
    const int tn = (t + 1 < T_STEPS) ? (t + 1) : t;
    const float* pn = xw + tn * NH;
    float xwn0 = (ib < NH) ? pn[ib] : 0.f;
    float xwn1 = (ib + 16 < NH) ? pn[ib + 16] : 0.f;
    float xwn2 = (ib + 32 < NH) ? pn[ib + 32] : 0.f;

    const _Float16* ab = &afrag[t & 1][0][0][0] + lane * 8;  // + kt*512
    f32x4 aE0 = zero4, aE1 = zero4, aE2 = zero4;
    f32x4 aO0 = zero4, aO1 = zero4, aO2 = zero4;
    half8 a0 = *(const half8*)(ab);
    half8 a1 = *(const half8*)(ab + 512);
#pragma unroll
    for (int kt = 0; kt < 12; ++kt) {
      half8 an = (kt + 2 < 12) ? *(const half8*)(ab + (kt + 2) * 512) : a0;
      if (kt & 1) {
        aO0 = __builtin_amdgcn_mfma_f32_16x16x32_f16(a0, bw[0][kt], aO0, 0, 0, 0);
        aO1 = __builtin_amdgcn_mfma_f32_16x16x32_f16(a0, bw[1][kt], aO1, 0, 0, 0);
        aO2 = __builtin_amdgcn_mfma_f32_16x16x32_f16(a0, bw[2][kt], aO2, 0, 0, 0);
      } else {
        aE0 = __builtin_amdgcn_mfma_f32_16x16x32_f16(a0, bw[0][kt], aE0, 0, 0, 0);
        aE1 = __builtin_amdgcn_mfma_f32_16x16x32_f16(a0, bw[1][kt], aE1, 0, 0, 0);
        aE2 = __builtin_amdgcn_mfma_f32_16x16x32_f16(a0, bw[2][kt], aE2, 0, 0, 0);
      }
      a0 = a1; a1 = an;
    }

    // epilogue: useful results on lanes 0..15, reg 0
    float s0 = aE0[0] + aO0[0] + xwv0;
    float s1 = aE1[0] + aO1[0] + xwv1;
    float s2 = aE2[0] + aO2[0] + xwv2;
    float h0 = 1.f - __fdividef(2.f, __expf(2.f * s0) + 1.f);
    float h1 = 1.f - __fdividef(2.f, __expf(2.f * s1) + 1.f);
    float h2 = 1.f - __fdividef(2.f, __expf(2.f * s2) + 1.f);

    if (lane < 16) {
      float* orow = hs + (size_t)t * NH;
      _Float16* nb = &afrag[(t + 1) & 1][0][0][0];
      if (ib < NH) {
        orow[ib] = h0;
        nb[(ib >> 5) * 512 + ((ib >> 3) & 3) * 128 + (ib & 7)] = (_Float16)h0;
      }
      if (ib + 16 < NH) {
        int k = ib + 16;
        orow[k] = h1;
        nb[(k >> 5) * 512 + ((k >> 3) & 3) * 128 + (k & 7)] = (_Float16)h1;
      }
      if (ib + 32 < NH) {
        int k = ib + 32;
        orow[k] = h2;
        nb[(k >> 5) * 512 + ((k >> 3) & 3) * 128 + (k & 7)] = (_Float16)h2;
      }
    }
    xwv0 = xwn0; xwv1 = xwn1; xwv2 = xwn2;
    __syncthreads();
  }
}

// ---------------------------------------------------------------------------
// k3: outcome_pre[t] = w_fc . hs[t] + b_fc   (one wave per timestep)
// ---------------------------------------------------------------------------
__global__ void k3_fc(const float* __restrict__ hs, const float* __restrict__ w_fc,
                      const float* __restrict__ b_fc, float* __restrict__ out0) {
  const int t = blockIdx.x * 4 + (threadIdx.x >> 6);
  const int lane = threadIdx.x & 63;
  const float* hrow = hs + (size_t)t * NH;
  float s = 0.f;
  for (int j = lane; j < NH; j += 64) s += w_fc[j] * hrow[j];
#pragma unroll
  for (int off = 32; off > 0; off >>= 1) s += __shfl_down(s, off, 64);
  if (lane == 0) out0[t] = s + b_fc[0];
}

extern "C" void kernel_launch(void* const* d_in, const int* in_sizes, int n_in,
                              void* d_out, int out_size, void* d_ws, size_t ws_size,
                              hipStream_t stream) {
  const float* angle  = (const float*)d_in[0];
  const float* rule   = (const float*)d_in[1];
  const float* w_rule = (const float*)d_in[2];
  const float* b_rule = (const float*)d_in[3];
  const float* w_ih   = (const float*)d_in[4];
  const float* w_hh   = (const float*)d_in[5];
  const float* b_ih   = (const float*)d_in[6];
  const float* b_hh   = (const float*)d_in[7];
  const float* w_fc   = (const float*)d_in[8];
  const float* b_fc   = (const float*)d_in[9];
  float* out = (float*)d_out;

  // workspace layout (floats): xw[T*NH] | A[NH] | C[NH] | w2t[NH*NH]
  float* xw  = (float*)d_ws;
  float* Av  = xw + (size_t)T_STEPS * NH;
  float* Cv  = Av + NH;
  float* w2t = Cv + NH;

  // S = e^kappa / (2*pi*I0(kappa)) = sqrt(kappa/(2*pi)) / asymptotic_series
  const double kappa = 1.0 / (0.1745 * 0.1745);
  double series = 1.0, term = 1.0;
  for (int k = 1; k < 16; ++k) {
    term *= ((2.0 * k - 1.0) * (2.0 * k - 1.0)) / (8.0 * kappa * (double)k);
    series += term;
  }
  const float vmS = (float)(sqrt(kappa / (2.0 * PI_D)) / series);

  k0_prep<<<(NH * NH + 255) / 256, 256, 0, stream>>>(w_ih, w_rule, b_rule, b_ih, b_hh,
                                                     Av, Cv, w2t);
  k1_xw<<<T_STEPS / 32, 256, 0, stream>>>(angle, rule, Av, Cv, w2t, xw,
                                          (float)kappa, vmS);
  k2_rnn<<<1, 512, 0, stream>>>(w_hh, xw, out + T_STEPS);
  k3_fc<<<T_STEPS / 4, 256, 0, stream>>>(out + T_STEPS, w_fc, b_fc, out);
}

// Round 2
// 15339.041 us; speedup vs baseline: 1.0033x; 1.0033x over previous
//
#include <hip/hip_runtime.h>
#include <cmath>

#define T_STEPS 16384
#define NH 361
#define NIN 489
#define NRULE 128

typedef _Float16 half8 __attribute__((ext_vector_type(8)));
typedef _Float16 half2v __attribute__((ext_vector_type(2)));

static constexpr double PI_D = 3.14159265358979323846;

// ---------------------------------------------------------------------------
// k0: one-time prep: transpose W2 = w_ih[:,128:] into w2t[j][i], and fold
//     A[i] = w_ih[i,:128] @ w_rule,  C[i] = w_ih[i,:128] @ b_rule + b_ih + b_hh
// ---------------------------------------------------------------------------
__global__ void k0_prep(const float* __restrict__ w_ih, const float* __restrict__ w_rule,
                        const float* __restrict__ b_rule, const float* __restrict__ b_ih,
                        const float* __restrict__ b_hh,
                        float* __restrict__ Av, float* __restrict__ Cv,
                        float* __restrict__ w2t) {
  int idx = blockIdx.x * 256 + threadIdx.x;
  if (idx < NH * NH) {
    int i = idx % NH;       // output row of w_ih
    int j = idx / NH;       // angle-grid column
    w2t[idx] = w_ih[i * NIN + NRULE + j];   // w2t[j*NH + i]
  }
  if (idx < NH) {
    float a = 0.f, c = 0.f;
    for (int k = 0; k < NRULE; ++k) {
      float w = w_ih[idx * NIN + k];
      a += w * w_rule[k];
      c += w * b_rule[k];
    }
    Av[idx] = a;
    Cv[idx] = c + b_ih[idx] + b_hh[idx];
  }
}

// ---------------------------------------------------------------------------
// k1: xw[t][i] = sum_j w2t[j][i]*vm[t][j] + rule[t]*A[i] + C[i]
// ---------------------------------------------------------------------------
__global__ void k1_xw(const float* __restrict__ angle, const float* __restrict__ rule,
                      const float* __restrict__ Av, const float* __restrict__ Cv,
                      const float* __restrict__ w2t, float* __restrict__ xw,
                      float kappa, float vmS) {
  __shared__ float vm[NH][32];
  __shared__ float srule[32];
  const int tid = threadIdx.x;
  const int t0 = blockIdx.x * 32;
  const float DEG = (float)(PI_D / 180.0);

  for (int idx = tid; idx < NH * 32; idx += 256) {
    int j = idx >> 5;
    int tt = idx & 31;
    float mu = angle[t0 + tt] * DEG;
    float c = __cosf((float)j * DEG - mu);
    vm[j][tt] = vmS * __expf(kappa * (c - 1.f));
  }
  if (tid < 32) srule[tid] = rule[t0 + tid];
  __syncthreads();

  for (int i = tid; i < NH; i += 256) {
    float acc[32];
#pragma unroll
    for (int tt = 0; tt < 32; ++tt) acc[tt] = 0.f;
    for (int j = 0; j < NH; ++j) {
      float wv = w2t[j * NH + i];
#pragma unroll
      for (int tt = 0; tt < 32; ++tt) acc[tt] += wv * vm[j][tt];
    }
    float Ai = Av[i], Ci = Cv[i];
#pragma unroll
    for (int tt = 0; tt < 32; ++tt)
      xw[(t0 + tt) * NH + i] = acc[tt] + srule[tt] * Ai + Ci;
  }
}

// ---------------------------------------------------------------------------
// k2: sequential RNN on the VALU via v_dot2_f32_f16.
//   768 threads = 12 waves (3/SIMD). Thread (i = tid>>1, kh = tid&1) computes
//   the kh-th K-half (192 of 384 padded) of out[i] = sum_k W[i][k] h[k].
//   W half-row lives in 24 half8 VGPRs (96 regs, f16). h is broadcast from a
//   dense LDS buffer (even/odd lanes hit disjoint banks via 208-elem stride).
//   Pair-combine with shfl_xor(1); tanh; even thread writes h back.
//   One barrier per step, double-buffered h.
// ---------------------------------------------------------------------------
#define KHALF 192
#define HSTRIDE 208   // f16 elems; 416 B -> odd half lands on disjoint banks

__device__ inline float dot8(half8 a, half8 b, float acc) {
  acc = __builtin_amdgcn_fdot2(__builtin_shufflevector(a, a, 0, 1),
                               __builtin_shufflevector(b, b, 0, 1), acc, false);
  acc = __builtin_amdgcn_fdot2(__builtin_shufflevector(a, a, 2, 3),
                               __builtin_shufflevector(b, b, 2, 3), acc, false);
  acc = __builtin_amdgcn_fdot2(__builtin_shufflevector(a, a, 4, 5),
                               __builtin_shufflevector(b, b, 4, 5), acc, false);
  acc = __builtin_amdgcn_fdot2(__builtin_shufflevector(a, a, 6, 7),
                               __builtin_shufflevector(b, b, 6, 7), acc, false);
  return acc;
}

__global__ __launch_bounds__(768, 3) void k2_rnn(const float* __restrict__ w_hh,
                                                 const float* __restrict__ xw,
                                                 float* __restrict__ hs) {
  __shared__ __align__(16) _Float16 hbuf[2][2 * HSTRIDE];
  const int tid = threadIdx.x;
  const int i = tid >> 1;        // output index 0..383
  const int kh = tid & 1;        // k-half
  const bool act = (i < NH);

  // zero both buffers (h0 = 0, and pads stay 0 forever)
  for (int idx = tid; idx < 4 * HSTRIDE; idx += 768)
    ((_Float16*)hbuf)[idx] = (_Float16)0.f;

  // W half-row -> 24 half8 regs (f16), zero-padded
  half8 w[24];
#pragma unroll
  for (int c = 0; c < 24; ++c) {
    half8 v;
#pragma unroll
    for (int e = 0; e < 8; ++e) {
      const int k = kh * KHALF + c * 8 + e;
      float x = (act && k < NH) ? w_hh[i * NH + k] : 0.f;
      v[e] = (_Float16)x;
    }
    w[c] = v;
  }

  float xwv = act ? xw[i] : 0.f;
  __syncthreads();

  for (int t = 0; t < T_STEPS; ++t) {
    const _Float16* hb = &hbuf[t & 1][kh * HSTRIDE];

    // prologue: 4 chunks in flight
    half8 c0 = *(const half8*)(hb);
    half8 c1 = *(const half8*)(hb + 8);
    half8 c2 = *(const half8*)(hb + 16);
    half8 c3 = *(const half8*)(hb + 24);

    // prefetch next step's xw under the dot phase
    const int tn = (t + 1 < T_STEPS) ? (t + 1) : t;
    float xwn = act ? xw[(size_t)tn * NH + i] : 0.f;

    float a0 = 0.f, a1 = 0.f, a2 = 0.f, a3 = 0.f;
#pragma unroll
    for (int g = 0; g < 6; ++g) {
      half8 n0 = c0, n1 = c1, n2 = c2, n3 = c3;
      if (g < 5) {
        const _Float16* p = hb + (g + 1) * 32;
        n0 = *(const half8*)(p);
        n1 = *(const half8*)(p + 8);
        n2 = *(const half8*)(p + 16);
        n3 = *(const half8*)(p + 24);
      }
      a0 = dot8(c0, w[g * 4 + 0], a0);
      a1 = dot8(c1, w[g * 4 + 1], a1);
      a2 = dot8(c2, w[g * 4 + 2], a2);
      a3 = dot8(c3, w[g * 4 + 3], a3);
      c0 = n0; c1 = n1; c2 = n2; c3 = n3;
    }

    float s = (a0 + a1) + (a2 + a3);
    s += __shfl_xor(s, 1, 64);     // combine the two K-halves

    if (act && kh == 0) {
      s += xwv;
      const float e = __expf(2.f * s);
      const float h = 1.f - __fdividef(2.f, e + 1.f);
      hs[(size_t)t * NH + i] = h;
      const int di = (i < KHALF) ? i : (HSTRIDE + i - KHALF);
      hbuf[(t + 1) & 1][di] = (_Float16)h;
    }
    xwv = xwn;
    __syncthreads();
  }
}

// ---------------------------------------------------------------------------
// k3: outcome_pre[t] = w_fc . hs[t] + b_fc   (one wave per timestep)
// ---------------------------------------------------------------------------
__global__ void k3_fc(const float* __restrict__ hs, const float* __restrict__ w_fc,
                      const float* __restrict__ b_fc, float* __restrict__ out0) {
  const int t = blockIdx.x * 4 + (threadIdx.x >> 6);
  const int lane = threadIdx.x & 63;
  const float* hrow = hs + (size_t)t * NH;
  float s = 0.f;
  for (int j = lane; j < NH; j += 64) s += w_fc[j] * hrow[j];
#pragma unroll
  for (int off = 32; off > 0; off >>= 1) s += __shfl_down(s, off, 64);
  if (lane == 0) out0[t] = s + b_fc[0];
}

extern "C" void kernel_launch(void* const* d_in, const int* in_sizes, int n_in,
                              void* d_out, int out_size, void* d_ws, size_t ws_size,
                              hipStream_t stream) {
  const float* angle  = (const float*)d_in[0];
  const float* rule   = (const float*)d_in[1];
  const float* w_rule = (const float*)d_in[2];
  const float* b_rule = (const float*)d_in[3];
  const float* w_ih   = (const float*)d_in[4];
  const float* w_hh   = (const float*)d_in[5];
  const float* b_ih   = (const float*)d_in[6];
  const float* b_hh   = (const float*)d_in[7];
  const float* w_fc   = (const float*)d_in[8];
  const float* b_fc   = (const float*)d_in[9];
  float* out = (float*)d_out;

  // workspace layout (floats): xw[T*NH] | A[NH] | C[NH] | w2t[NH*NH]
  float* xw  = (float*)d_ws;
  float* Av  = xw + (size_t)T_STEPS * NH;
  float* Cv  = Av + NH;
  float* w2t = Cv + NH;

  // S = e^kappa / (2*pi*I0(kappa)) = sqrt(kappa/(2*pi)) / asymptotic_series
  const double kappa = 1.0 / (0.1745 * 0.1745);
  double series = 1.0, term = 1.0;
  for (int k = 1; k < 16; ++k) {
    term *= ((2.0 * k - 1.0) * (2.0 * k - 1.0)) / (8.0 * kappa * (double)k);
    series += term;
  }
  const float vmS = (float)(sqrt(kappa / (2.0 * PI_D)) / series);

  k0_prep<<<(NH * NH + 255) / 256, 256, 0, stream>>>(w_ih, w_rule, b_rule, b_ih, b_hh,
                                                     Av, Cv, w2t);
  k1_xw<<<T_STEPS / 32, 256, 0, stream>>>(angle, rule, Av, Cv, w2t, xw,
                                          (float)kappa, vmS);
  k2_rnn<<<1, 768, 0, stream>>>(w_hh, xw, out + T_STEPS);
  k3_fc<<<T_STEPS / 4, 256, 0, stream>>>(out + T_STEPS, w_fc, b_fc, out);
}